// Round 9
// baseline (3440.557 us; speedup 1.0000x reference)
//
#include <hip/hip_runtime.h>

// AttentionRNN: B=1024, T=256, U=256.
// Fused pipeline: per chunk c, ONE dispatch of 256 blocks x 512 threads:
//   blocks 0..127  : recurrent steps [c*CT,(c+1)*CT) reading P_cur (r7 structure:
//                    8 rows/block, 8 waves, MFMA qg, rolling P regs, lgkm barriers)
//                    + P values prefetched ONE FULL STEP ahead.
//   blocks 128..255: GEMM writing P_nxt (chunk c+1: slabs 0..CT+1 = t0'-2..t0'+CT-1),
//                    fp32 X read + in-register fp16 convert (no cast_x kernel).
// P double-buffered; GEMM recomputes the 2 overlap slabs each chunk. 85KB LDS
// forces 1 block/CU so the two roles never share a CU.

typedef _Float16 f16;
typedef _Float16 f16x8 __attribute__((ext_vector_type(8)));
typedef _Float16 f16x4 __attribute__((ext_vector_type(4)));
typedef float f32x4 __attribute__((ext_vector_type(4)));

static __device__ __forceinline__ f32x4 mfma16(f16x8 a, f16x8 b, f32x4 c){
  return __builtin_amdgcn_mfma_f32_16x16x32_f16(a, b, c, 0, 0, 0);
}
static __device__ __forceinline__ float sigmoid_f(float x){
  return 1.0f / (1.0f + __expf(-x));
}
static __device__ __forceinline__ float tanh_f(float x){
  float e = __expf(2.0f * x);
  return 1.0f - 2.0f / (e + 1.0f);   // stable
}
static __device__ __forceinline__ void lgkm_barrier(){
  asm volatile("s_waitcnt lgkmcnt(0)" ::: "memory");
  __builtin_amdgcn_s_barrier();
}

// ------------- cast weights to fp16 -------------
// WcatT rows: [0,256) Wemb^T, [256,1024) Wre^T, [1024,1792) Wnew^T  (N x K row-major)
// WsrF fragment-packed [ct64][kt8][lane64][e8]: col=ct*16+(lane&15), k=kt*32+((lane>>4)&3)*8+e
__global__ void cast_w_kernel(const float* __restrict__ EK, const float* __restrict__ RE,
    const float* __restrict__ NW, const float* __restrict__ SK, const float* __restrict__ RS,
    f16* __restrict__ WcatT, f16* __restrict__ WsrF){
  int tid = blockIdx.x * 256 + threadIdx.x;
  if (tid < 458752){
    int n = tid >> 8, k = tid & 255;
    float v;
    if (n < 256)       v = EK[k*256 + n];
    else if (n < 1024) v = RE[k*768 + (n-256)];
    else               v = NW[k*768 + (n-1024)];
    WcatT[n*256 + k] = (f16)v;
  } else {
    int idx = tid - 458752;            // 0..262143
    int e    = idx & 7;
    int lane = (idx >> 3) & 63;
    int kt   = (idx >> 9) & 7;
    int ct   = idx >> 12;              // 0..63
    int col  = ct*16 + (lane & 15);
    int k    = kt*32 + ((lane >> 4) & 3)*8 + e;
    float v = (col < 256) ? SK[k*256 + col] : RS[k*768 + (col-256)];
    WsrF[idx] = (f16)v;
  }
}

// one kt-stage of the qg MFMA: 8 MFMAs, refill av (LDS) and this W slot.
// (KT+4)&7: stages 0-3 refill this step's kt4-7, stages 4-7 refill NEXT step's kt0-3.
template<int KT>
static __device__ __forceinline__ void stage(f32x4 (&acc)[8], f16x8 (&WS)[8], f16x8& av,
    const f16* stA_l, const f16* wb_l){
  #pragma unroll
  for (int c = 0; c < 8; ++c) acc[c] = mfma16(av, WS[c], acc[c]);
  if (KT < 6) av = *(const f16x8*)(stA_l + (KT+2)*520);
  #pragma unroll
  for (int c = 0; c < 8; ++c)
    WS[c] = *(const f16x8*)(wb_l + (c*8 + ((KT+4)&7))*512);
}

// ---------------- fused kernel: 256 blocks x 512 threads ----------------
__global__ __launch_bounds__(512, 1) void fused_kernel(
    const f16* __restrict__ Pcur, f16* __restrict__ Pnxt,
    const float* __restrict__ X, const f16* __restrict__ WcatT,
    const f16* __restrict__ WsrF,
    const float* __restrict__ bias, const float* __restrict__ Lk,
    float* __restrict__ state, float* __restrict__ out,
    int t0, int nsteps, int gemm_t0, int gemm_mtiles, int gemm_slab_off)
{
  __shared__ float qg[8*1153 + 1056];   // 9-word-group layout + pad (forces 1 block/CU)
  __shared__ f16  stA[8*520];           // state f16, fragment-major [kt][lane][8]
  __shared__ float sb9[288], sl9[288];
  __shared__ f16 As[128*64];
  __shared__ f16 Bs[128*64];

  const int tid = threadIdx.x;
  const size_t SL = 1024ull*1792ull;

  if (blockIdx.x < 128){
    // ======================= recurrent role =======================
    if (nsteps == 0) return;
    const int l = tid & 63, w = tid >> 6;          // 8 waves, wave w owns row w
    const int r0 = blockIdx.x * 8;
    const int agrp = l >> 4;
    const int c4 = l * 4;                          // 4 cols/lane
    const int gb = r0 + w;
    const size_t gbo = (size_t)gb*1792;

    const int qw_s = (l >> 1)*9 + (l & 1)*4;
    const int qgw  = (w*16 + ((l & 15) >> 3))*9 + (l & 7);

    if (tid < 256){ int wd = (tid >> 3)*9 + (tid & 7); sb9[wd] = bias[tid]; sl9[wd] = Lk[tid]; }
    for (int j = tid; j < 8*520; j += 512) stA[j] = (f16)0.f;
    __syncthreads();

    f32x4 sn = *(const f32x4*)(state + (size_t)gb*256 + c4);
    f16* const sa = &stA[(l >> 3)*520 + ((((l >> 1) & 3) << 4) + w)*8 + (l & 1)*4];
    { f16x4 h; h[0]=(f16)sn[0]; h[1]=(f16)sn[1]; h[2]=(f16)sn[2]; h[3]=(f16)sn[3]; *(f16x4*)sa = h; }

    const f16* const wb_l  = WsrF + (size_t)w*32768 + l*8;
    const f16* const stA_l = &stA[l*8];

    // weight slots kt0..3 (persist across steps)
    f16x8 W0[8], W1[8], W2[8], W3[8];
    #pragma unroll
    for (int c = 0; c < 8; ++c) W0[c] = *(const f16x8*)(wb_l + (c*8 + 0)*512);
    #pragma unroll
    for (int c = 0; c < 8; ++c) W1[c] = *(const f16x8*)(wb_l + (c*8 + 1)*512);
    #pragma unroll
    for (int c = 0; c < 8; ++c) W2[c] = *(const f16x8*)(wb_l + (c*8 + 2)*512);
    #pragma unroll
    for (int c = 0; c < 8; ++c) W3[c] = *(const f16x8*)(wb_l + (c*8 + 3)*512);

    // rolling P registers from slabs 0 (t0-2), 1 (t0-1)
    f16x4 E0 = *(const f16x4*)(Pcur + gbo + c4);
    f16x4 E1 = *(const f16x4*)(Pcur + SL + gbo + c4);
    f16x4 U2 = *(const f16x4*)(Pcur + gbo + 256 + c4);
    f16x4 R2 = *(const f16x4*)(Pcur + gbo + 512 + c4);
    f16x4 C2 = *(const f16x4*)(Pcur + gbo + 768 + c4);
    f16x4 U1 = *(const f16x4*)(Pcur + SL + gbo + 256 + c4);
    f16x4 R1 = *(const f16x4*)(Pcur + SL + gbo + 512 + c4);
    f16x4 C1 = *(const f16x4*)(Pcur + SL + gbo + 768 + c4);
    // step-0 cold set from slab 2 (prefetched; consumed in step 0 phase 2)
    const f16* pc0 = Pcur + 2*SL + gbo;
    f16x4 cE2 = *(const f16x4*)(pc0 + c4);
    f16x4 cUc = *(const f16x4*)(pc0 +  256 + c4);
    f16x4 cRc = *(const f16x4*)(pc0 +  512 + c4);
    f16x4 cCc = *(const f16x4*)(pc0 +  768 + c4);
    f16x4 cNU = *(const f16x4*)(pc0 + 1024 + c4);
    f16x4 cNR = *(const f16x4*)(pc0 + 1280 + c4);
    f16x4 cNC = *(const f16x4*)(pc0 + 1536 + c4);
    __syncthreads();

    for (int i = 0; i < nsteps; ++i){
      const int t = t0 + i;
      // prefetch NEXT step's cold set (slab i+3, clamped) -- a full step in flight
      const int ns = (i+3 < nsteps+2) ? (i+3) : (nsteps+1);
      const f16* pn = Pcur + (size_t)ns*SL + gbo;
      f16x4 nE2 = *(const f16x4*)(pn + c4);
      f16x4 nUc = *(const f16x4*)(pn +  256 + c4);
      f16x4 nRc = *(const f16x4*)(pn +  512 + c4);
      f16x4 nCc = *(const f16x4*)(pn +  768 + c4);
      f16x4 nNU = *(const f16x4*)(pn + 1024 + c4);
      f16x4 nNR = *(const f16x4*)(pn + 1280 + c4);
      f16x4 nNC = *(const f16x4*)(pn + 1536 + c4);

      f16x8 av0 = *(const f16x8*)(stA_l + 0*520);
      f16x8 av1 = *(const f16x8*)(stA_l + 1*520);
      f32x4 acc[8];
      #pragma unroll
      for (int c = 0; c < 8; ++c) acc[c] = (f32x4){0.f,0.f,0.f,0.f};

      stage<0>(acc, W0, av0, stA_l, wb_l);
      stage<1>(acc, W1, av1, stA_l, wb_l);
      stage<2>(acc, W2, av0, stA_l, wb_l);
      stage<3>(acc, W3, av1, stA_l, wb_l);
      stage<4>(acc, W0, av0, stA_l, wb_l);
      stage<5>(acc, W1, av1, stA_l, wb_l);
      stage<6>(acc, W2, av0, stA_l, wb_l);
      stage<7>(acc, W3, av1, stA_l, wb_l);

      if (agrp < 2){
        #pragma unroll
        for (int c = 0; c < 8; ++c){
          #pragma unroll
          for (int j = 0; j < 4; ++j)
            qg[(agrp*4 + j)*1153 + qgw + c*18] = acc[c][j];
        }
      }
      lgkm_barrier();

      // ---- scores + softmax (full wave on row w; P values already resident) ----
      const float* qrow = &qg[w*1153];
      const f32x4 q  = *(const f32x4*)(qrow + qw_s);
      const f32x4 bb = *(const f32x4*)(sb9 + qw_s);
      const f32x4 lk = *(const f32x4*)(sl9 + qw_s);
      float s0 = 0.f, s1 = 0.f, s2 = 0.f;
      #pragma unroll
      for (int j = 0; j < 4; ++j){
        const float qb = q[j] + bb[j];
        s0 += tanh_f((float)E0[j]  + qb) * lk[j];
        s1 += tanh_f((float)E1[j]  + qb) * lk[j];
        s2 += tanh_f((float)cE2[j] + qb) * lk[j];
      }
      #pragma unroll
      for (int off = 32; off; off >>= 1){
        s0 += __shfl_xor(s0, off);
        s1 += __shfl_xor(s1, off);
        s2 += __shfl_xor(s2, off);
      }
      const float mx = fmaxf(fmaxf(s0, s1), s2);
      const float x0 = __expf(s0 - mx), x1 = __expf(s1 - mx), x2 = __expf(s2 - mx);
      const float inv = 1.0f / (x0 + x1 + x2);
      const float pr0 = x0*inv, pr1 = x1*inv, pr2 = x2*inv;

      // ---- GRU (row w, 4 cols/lane, state in regs) ----
      const f32x4 qu = *(const f32x4*)(qrow + (32 + (l >> 1))*9 + (l & 1)*4);
      const f32x4 qr = *(const f32x4*)(qrow + (64 + (l >> 1))*9 + (l & 1)*4);
      const f32x4 qc = *(const f32x4*)(qrow + (96 + (l >> 1))*9 + (l & 1)*4);
      #pragma unroll
      for (int j = 0; j < 4; ++j){
        const float geu = pr2*(float)cUc[j] + pr1*(float)U1[j] + pr0*(float)U2[j];
        const float ger = pr2*(float)cRc[j] + pr1*(float)R1[j] + pr0*(float)R2[j];
        const float gec = pr2*(float)cCc[j] + pr1*(float)C1[j] + pr0*(float)C2[j];
        const float up   = sigmoid_f(qu[j] + geu + (float)cNU[j]);
        const float rp   = sigmoid_f(qr[j] + ger + (float)cNR[j]);
        const float cand = tanh_f(rp*qc[j] + gec + (float)cNC[j]);
        sn[j] = (1.0f - up)*sn[j] + up*cand;
      }
      { f16x4 h; h[0]=(f16)sn[0]; h[1]=(f16)sn[1]; h[2]=(f16)sn[2]; h[3]=(f16)sn[3]; *(f16x4*)sa = h; }
      if (t == 255) *(f32x4*)(out + (size_t)gb*256 + c4) = sn;

      // roll P registers forward; swap in prefetched next-step set
      E0 = E1; E1 = cE2;
      U2 = U1; U1 = cUc; R2 = R1; R1 = cRc; C2 = C1; C1 = cCc;
      cE2 = nE2; cUc = nUc; cRc = nRc; cCc = nCc; cNU = nNU; cNR = nNR; cNC = nNC;
      lgkm_barrier();
    }
    *(f32x4*)(state + (size_t)gb*256 + c4) = sn;

  } else {
    // ======================= GEMM role (next chunk's P) =======================
    if (gemm_mtiles == 0) return;
    const int bid2 = blockIdx.x - 128;
    const int l = tid & 63, wid = tid >> 6;     // 8 waves: 4 (rows) x 2 (cols)
    const int wr = wid >> 1, wc = wid & 1;
    const int sr  = tid >> 3;                   // 0..63 staging rows (and +64)
    const int sc8 = (tid & 7) * 8;
    const int jobs = gemm_mtiles * 14;
    f16* const Cb = Pnxt + (size_t)gemm_slab_off * SL;

    for (int job = bid2; job < jobs; job += 128){
      const int mt = job / 14, nt = job % 14;
      const int tsl = mt >> 3;
      const int b0  = (mt & 7) * 128;
      const int tt  = gemm_t0 + tsl;
      const int n0  = nt * 128;

      f32x4 acc[2][4];
      #pragma unroll
      for (int mi = 0; mi < 2; ++mi)
        #pragma unroll
        for (int ni = 0; ni < 4; ++ni)
          acc[mi][ni] = (f32x4){0.f,0.f,0.f,0.f};

      for (int kt = 0; kt < 4; ++kt){
        #pragma unroll
        for (int h = 0; h < 2; ++h){
          const int row = sr + h*64;
          f32x4 a0 = *(const f32x4*)(X + (size_t)(b0+row)*65536 + (size_t)tt*256 + kt*64 + sc8);
          f32x4 a1 = *(const f32x4*)(X + (size_t)(b0+row)*65536 + (size_t)tt*256 + kt*64 + sc8 + 4);
          f16x8 ha;
          #pragma unroll
          for (int jj = 0; jj < 8; ++jj) ha[jj] = (f16)((jj < 4) ? a0[jj] : a1[jj-4]);
          const int e = (row*64 + sc8) ^ ((row & 7) << 3);
          *(f16x8*)&As[e] = ha;
          *(f16x8*)&Bs[e] = *(const f16x8*)(WcatT + (size_t)(n0+row)*256 + kt*64 + sc8);
        }
        __syncthreads();
        #pragma unroll
        for (int kk = 0; kk < 2; ++kk){
          f16x8 af[2], bfr[4];
          #pragma unroll
          for (int mi = 0; mi < 2; ++mi){
            const int row = wr*32 + mi*16 + (l & 15);
            const int e = (row*64 + kk*32 + (l >> 4)*8) ^ ((row & 7) << 3);
            af[mi] = *(const f16x8*)&As[e];
          }
          #pragma unroll
          for (int ni = 0; ni < 4; ++ni){
            const int row = wc*64 + ni*16 + (l & 15);
            const int e = (row*64 + kk*32 + (l >> 4)*8) ^ ((row & 7) << 3);
            bfr[ni] = *(const f16x8*)&Bs[e];
          }
          #pragma unroll
          for (int mi = 0; mi < 2; ++mi)
            #pragma unroll
            for (int ni = 0; ni < 4; ++ni)
              acc[mi][ni] = mfma16(af[mi], bfr[ni], acc[mi][ni]);
        }
        __syncthreads();
      }
      const size_t m0 = (size_t)mt * 128;
      #pragma unroll
      for (int mi = 0; mi < 2; ++mi){
        #pragma unroll
        for (int ni = 0; ni < 4; ++ni){
          const int col = n0 + wc*64 + ni*16 + (l & 15);
          const size_t row = m0 + wr*32 + mi*16 + ((l >> 4) * 4);
          #pragma unroll
          for (int j = 0; j < 4; ++j)
            Cb[(row + j) * 1792 + col] = (f16)acc[mi][ni][j];
        }
      }
    }
  }
}

// ---------------------------------- launch ----------------------------------
extern "C" void kernel_launch(void* const* d_in, const int* in_sizes, int n_in,
                              void* d_out, int out_size, void* d_ws, size_t ws_size,
                              hipStream_t stream)
{
  const float* X  = (const float*)d_in[0];
  const float* EK = (const float*)d_in[1];
  const float* SK = (const float*)d_in[2];
  const float* BI = (const float*)d_in[3];
  const float* LK = (const float*)d_in[4];
  const float* RS = (const float*)d_in[5];
  const float* RE = (const float*)d_in[6];
  const float* NW = (const float*)d_in[7];
  float* out = (float*)d_out;
  char* ws = (char*)d_ws;

  const size_t slabB = 1024ull * 1792ull * 2ull;   // 3,670,016 B
  const size_t wB    = 917504ull + 524288ull + 1048576ull;
  int CT = 4;
  if      (ws_size >= 2ull*34ull*slabB + wB) CT = 32;
  else if (ws_size >= 2ull*18ull*slabB + wB) CT = 16;
  else if (ws_size >= 2ull*10ull*slabB + wB) CT = 8;

  f16* P0 = (f16*)ws;
  f16* P1 = (f16*)(ws + (size_t)(CT + 2) * slabB);
  size_t poff = 2ull * (size_t)(CT + 2) * slabB;
  f16* WcatT = (f16*)(ws + poff);
  f16* WsrF  = (f16*)(ws + poff + 917504ull);
  float* state = (float*)(ws + poff + 917504ull + 524288ull);

  hipMemsetAsync(state, 0, 1048576ull, stream);
  hipMemsetAsync(P0, 0, 2ull*slabB, stream);       // zero "virtual" slabs t=-2,-1
  cast_w_kernel<<<2816, 256, 0, stream>>>(EK, RE, NW, SK, RS, WcatT, WsrF);

  const int nch = 256 / CT;
  // prologue: GEMM-only dispatch fills P0 slabs 2..CT+1 (t = 0..CT-1)
  fused_kernel<<<256, 512, 0, stream>>>(P0, P0, X, WcatT, WsrF, BI, LK,
                                        state, out, 0, 0, 0, CT*8, 2);
  for (int c = 0; c < nch; ++c){
    f16* Pc = (c & 1) ? P1 : P0;
    f16* Pn = (c & 1) ? P0 : P1;
    const int gm  = (c + 1 < nch) ? (CT + 2) * 8 : 0;
    const int gt0 = (c + 1) * CT - 2;
    fused_kernel<<<256, 512, 0, stream>>>(Pc, Pn, X, WcatT, WsrF, BI, LK,
                                          state, out, c*CT, CT, gt0, gm, 0);
  }
}

// Round 10
// 1931.710 us; speedup vs baseline: 1.7811x; 1.7811x over previous
//
#include <hip/hip_runtime.h>

// AttentionRNN: B=1024, T=256, U=256.
//  Xh = fp16(X); P[t] = x_t @ [Wemb|Wre|Wnew] (fp16 MFMA GEMM, CT chunks, P L3-resident).
//  Recurrent v2 (PERSISTENT WEIGHTS): 128 blocks x 8 rows x 8 waves. Wave w owns
//  batch row r0+w and qg cols [w*128,(w+1)*128). Wsr is resident: kt0..5 in 192
//  VGPRs/wave (loaded once, live across the step loop), kt6..7 in 128 KB LDS
//  (preloaded once). ZERO per-step weight traffic -> the per-CU L1-miss stream
//  that capped r7 at ~10 us/step is gone. qg stored as f16 in LDS (fits 160 KB).
//  P cold loads issued at step start (global, survive lgkm-only barriers); warm
//  P re-read from L2 in phase 2.

typedef _Float16 f16;
typedef _Float16 f16x8 __attribute__((ext_vector_type(8)));
typedef _Float16 f16x4 __attribute__((ext_vector_type(4)));
typedef float f32x4 __attribute__((ext_vector_type(4)));

static __device__ __forceinline__ f32x4 mfma16(f16x8 a, f16x8 b, f32x4 c){
  return __builtin_amdgcn_mfma_f32_16x16x32_f16(a, b, c, 0, 0, 0);
}
static __device__ __forceinline__ float sigmoid_f(float x){
  return 1.0f / (1.0f + __expf(-x));
}
static __device__ __forceinline__ float tanh_f(float x){
  float e = __expf(2.0f * x);
  return 1.0f - 2.0f / (e + 1.0f);   // stable
}
static __device__ __forceinline__ void lgkm_barrier(){
  asm volatile("s_waitcnt lgkmcnt(0)" ::: "memory");
  __builtin_amdgcn_s_barrier();
}

// ---------------- cast X fp32 -> fp16 (same layout) ----------------
__global__ void cast_x_kernel(const float* __restrict__ X, f16* __restrict__ Xh){
  size_t e = ((size_t)blockIdx.x * 256 + threadIdx.x) * 8;
  f32x4 v0 = *(const f32x4*)(X + e);
  f32x4 v1 = *(const f32x4*)(X + e + 4);
  f16x8 h;
  #pragma unroll
  for (int j = 0; j < 8; ++j) h[j] = (f16)((j < 4) ? v0[j] : v1[j-4]);
  *(f16x8*)(Xh + e) = h;
}

// ------------- cast weights to fp16 -------------
// WcatT rows: [0,256) Wemb^T, [256,1024) Wre^T, [1024,1792) Wnew^T  (N x K row-major)
// WsrF fragment-packed [ct64][kt8][lane64][e8]: col=ct*16+(lane&15), k=kt*32+((lane>>4)&3)*8+e
__global__ void cast_w_kernel(const float* __restrict__ EK, const float* __restrict__ RE,
    const float* __restrict__ NW, const float* __restrict__ SK, const float* __restrict__ RS,
    f16* __restrict__ WcatT, f16* __restrict__ WsrF){
  int tid = blockIdx.x * 256 + threadIdx.x;
  if (tid < 458752){
    int n = tid >> 8, k = tid & 255;
    float v;
    if (n < 256)       v = EK[k*256 + n];
    else if (n < 1024) v = RE[k*768 + (n-256)];
    else               v = NW[k*768 + (n-1024)];
    WcatT[n*256 + k] = (f16)v;
  } else {
    int idx = tid - 458752;            // 0..262143
    int e    = idx & 7;
    int lane = (idx >> 3) & 63;
    int kt   = (idx >> 9) & 7;
    int ct   = idx >> 12;              // 0..63
    int col  = ct*16 + (lane & 15);
    int k    = kt*32 + ((lane >> 4) & 3)*8 + e;
    float v = (col < 256) ? SK[k*256 + col] : RS[k*768 + (col-256)];
    WsrF[idx] = (f16)v;
  }
}

// ---- GEMM: C[r=tsl*1024+b][0:1792) = Xh[b][t_start+tsl][:] @ WcatT^T ----
__global__ __launch_bounds__(256, 2) void gemm_f16_kernel(
    const f16* __restrict__ Xh, const f16* __restrict__ Bm,
    f16* __restrict__ C, int Mtiles, int t_start)
{
  __shared__ f16 As[128*64];
  __shared__ f16 Bs[128*64];
  const int NT = 14;
  const int nwg = Mtiles * NT;
  int bid = blockIdx.x, wg = bid;
  if ((nwg & 7) == 0){ int cpx = nwg >> 3; wg = (bid & 7) * cpx + (bid >> 3); }
  const int mt = wg / NT, nt = wg % NT;
  const int tsl = mt >> 3;
  const int b0  = (mt & 7) * 128;
  const int t   = t_start + tsl;
  const int n0  = nt * 128;
  const int tid = threadIdx.x;
  const int l = tid & 63, wid = tid >> 6;
  const int wr = wid >> 1, wc = wid & 1;
  const int srow = tid >> 3;
  const int scol = (tid & 7) * 8;

  const size_t ASTR = 32ull * 65536ull;
  const f16* Ab = Xh + ((size_t)(b0 + srow) * 256 + t) * 256 + scol;
  const f16* Bb = Bm + ((size_t)(n0 + srow)) * 256 + scol;

  f16x8 ra[4], rb[4];
  #pragma unroll
  for (int j = 0; j < 4; ++j){
    ra[j] = *(const f16x8*)(Ab + (size_t)j * ASTR);
    rb[j] = *(const f16x8*)(Bb + (size_t)j * 32 * 256);
  }

  f32x4 acc[4][4];
  #pragma unroll
  for (int mi = 0; mi < 4; ++mi)
    #pragma unroll
    for (int ni = 0; ni < 4; ++ni)
      acc[mi][ni] = (f32x4){0.f,0.f,0.f,0.f};

  for (int kt = 0; kt < 4; ++kt){
    #pragma unroll
    for (int j = 0; j < 4; ++j){
      int row = srow + j*32;
      int e = (row*64 + scol) ^ ((row & 7) << 3);
      *(f16x8*)&As[e] = ra[j];
      *(f16x8*)&Bs[e] = rb[j];
    }
    __syncthreads();
    if (kt < 3){
      #pragma unroll
      for (int j = 0; j < 4; ++j){
        ra[j] = *(const f16x8*)(Ab + (kt+1)*64 + (size_t)j * ASTR);
        rb[j] = *(const f16x8*)(Bb + (kt+1)*64 + (size_t)j * 32 * 256);
      }
    }
    #pragma unroll
    for (int kk = 0; kk < 2; ++kk){
      f16x8 af[4], bfr[4];
      #pragma unroll
      for (int mi = 0; mi < 4; ++mi){
        int row = wr*64 + mi*16 + (l & 15);
        int e = (row*64 + kk*32 + (l >> 4)*8) ^ ((row & 7) << 3);
        af[mi] = *(const f16x8*)&As[e];
      }
      #pragma unroll
      for (int ni = 0; ni < 4; ++ni){
        int row = wc*64 + ni*16 + (l & 15);
        int e = (row*64 + kk*32 + (l >> 4)*8) ^ ((row & 7) << 3);
        bfr[ni] = *(const f16x8*)&Bs[e];
      }
      #pragma unroll
      for (int mi = 0; mi < 4; ++mi)
        #pragma unroll
        for (int ni = 0; ni < 4; ++ni)
          acc[mi][ni] = mfma16(af[mi], bfr[ni], acc[mi][ni]);
    }
    __syncthreads();
  }
  const size_t m0 = (size_t)mt * 128;
  #pragma unroll
  for (int mi = 0; mi < 4; ++mi){
    #pragma unroll
    for (int ni = 0; ni < 4; ++ni){
      int col = n0 + wc*64 + ni*16 + (l & 15);
      size_t row = m0 + wr*64 + mi*16 + ((l >> 4) * 4);
      #pragma unroll
      for (int j = 0; j < 4; ++j)
        C[(row + j) * 1792 + col] = (f16)acc[mi][ni][j];
    }
  }
}

// ---------- recurrent v2: 128 blocks x 8 rows, 512 threads (8 waves) ----------
__global__ __launch_bounds__(512, 1) void recurrent_kernel(
    const f16* __restrict__ P, const f16* __restrict__ WsrF,
    const float* __restrict__ bias, const float* __restrict__ Lk,
    float* __restrict__ state, float* __restrict__ out,
    int t0, int nsteps)
{
  __shared__ f16 Wl[8*8192];             // weights kt6..7: [w][ct*2+(kt-6)][lane][8] = 128 KB
  __shared__ f16 qg16[8*1032];           // qg as f16: [row][1032], stride 2064 B
  __shared__ f16 stA[8*520];             // state f16, fragment-major [kt][lane][8]
  __shared__ __align__(16) float sb[256];
  __shared__ __align__(16) float sl[256];

  const int tid = threadIdx.x;
  const int l = tid & 63, w = tid >> 6;  // 8 waves, wave w owns row w
  const int r0 = blockIdx.x * 8;
  const int arow = l & 15, agrp = l >> 4;
  const int c4 = l * 4;
  const int gb = r0 + w;
  const size_t SL = 1024ull*1792ull;
  const size_t gbo = (size_t)gb*1792;

  if (tid < 256){ sb[tid] = bias[tid]; sl[tid] = Lk[tid]; }
  for (int j = tid; j < 8*520; j += 512) stA[j] = (f16)0.f;

  // ---- persistent weights: kt0..5 -> 192 VGPRs/wave (loaded once, live in loop) ----
  const f16* const wbase = WsrF + (size_t)w*32768 + l*8;   // wave's 8 ct-tiles
  f16x8 Wreg[8][6];
  #pragma unroll
  for (int ct = 0; ct < 8; ++ct)
    #pragma unroll
    for (int kt = 0; kt < 6; ++kt)
      Wreg[ct][kt] = *(const f16x8*)(wbase + (ct*8 + kt)*512);
  // ---- kt6..7 -> LDS (128 KB, loaded once) ----
  #pragma unroll
  for (int ct = 0; ct < 8; ++ct)
    #pragma unroll
    for (int k2 = 0; k2 < 2; ++k2)
      *(f16x8*)&Wl[w*8192 + (ct*2 + k2)*512 + l*8] =
          *(const f16x8*)(wbase + (ct*8 + 6 + k2)*512);
  __syncthreads();

  f32x4 sn = *(const f32x4*)(state + (size_t)gb*256 + c4);
  f16* const sa = &stA[(l >> 3)*520 + ((((l >> 1) & 3) << 4) + w)*8 + (l & 1)*4];
  { f16x4 h; h[0]=(f16)sn[0]; h[1]=(f16)sn[1]; h[2]=(f16)sn[2]; h[3]=(f16)sn[3]; *(f16x4*)sa = h; }
  lgkm_barrier();

  for (int i = 0; i < nsteps; ++i){
    const int t = t0 + i;
    const f16* p2 = P + (size_t)(i+2)*SL + gbo;
    const f16* p1 = P + (size_t)(i+1)*SL + gbo;
    const f16* p0 = P + (size_t)(i+0)*SL + gbo;

    // ---- cold P loads (slab i+2, HBM): issued first, consumed in phase 2 ----
    const f16x4 cE2 = *(const f16x4*)(p2 + c4);
    const f16x4 cU  = *(const f16x4*)(p2 +  256 + c4);
    const f16x4 cR  = *(const f16x4*)(p2 +  512 + c4);
    const f16x4 cC  = *(const f16x4*)(p2 +  768 + c4);
    const f16x4 cNU = *(const f16x4*)(p2 + 1024 + c4);
    const f16x4 cNR = *(const f16x4*)(p2 + 1280 + c4);
    const f16x4 cNC = *(const f16x4*)(p2 + 1536 + c4);

    // ---- phase 1: qg = state @ Wsr, two half-passes over ct (acc[4] saves VGPRs) ----
    #pragma unroll
    for (int half = 0; half < 2; ++half){
      f32x4 acc[4];
      #pragma unroll
      for (int c = 0; c < 4; ++c) acc[c] = (f32x4){0.f,0.f,0.f,0.f};
      #pragma unroll
      for (int kt = 0; kt < 8; ++kt){
        const f16x8 av = *(const f16x8*)&stA[kt*520 + l*8];
        #pragma unroll
        for (int c = 0; c < 4; ++c){
          const int ct = half*4 + c;
          f16x8 B;
          if (kt < 6) B = Wreg[ct][kt];
          else        B = *(const f16x8*)&Wl[w*8192 + (ct*2 + (kt-6))*512 + l*8];
          acc[c] = mfma16(av, B, acc[c]);
        }
      }
      if (agrp < 2){
        #pragma unroll
        for (int c = 0; c < 4; ++c){
          const int col = w*128 + (half*4 + c)*16 + arow;
          #pragma unroll
          for (int j = 0; j < 4; ++j)
            qg16[(agrp*4 + j)*1032 + col] = (f16)acc[c][j];
        }
      }
    }
    lgkm_barrier();

    // ---- warm P loads (slabs i, i+1: L2-resident from prior steps) ----
    const f16x4 E0 = *(const f16x4*)(p0 + c4);
    const f16x4 E1 = *(const f16x4*)(p1 + c4);
    const f16x4 U1 = *(const f16x4*)(p1 + 256 + c4);
    const f16x4 R1 = *(const f16x4*)(p1 + 512 + c4);
    const f16x4 C1 = *(const f16x4*)(p1 + 768 + c4);
    const f16x4 U2 = *(const f16x4*)(p0 + 256 + c4);
    const f16x4 R2 = *(const f16x4*)(p0 + 512 + c4);
    const f16x4 C2 = *(const f16x4*)(p0 + 768 + c4);

    // ---- scores + softmax (full wave on row w) ----
    const f16x4 qv = *(const f16x4*)&qg16[w*1032 + c4];
    const f32x4 bb = *(const f32x4*)&sb[c4];
    const f32x4 lk = *(const f32x4*)&sl[c4];
    float s0 = 0.f, s1 = 0.f, s2 = 0.f;
    #pragma unroll
    for (int j = 0; j < 4; ++j){
      const float qb = (float)qv[j] + bb[j];
      s0 += tanh_f((float)E0[j]  + qb) * lk[j];
      s1 += tanh_f((float)E1[j]  + qb) * lk[j];
      s2 += tanh_f((float)cE2[j] + qb) * lk[j];
    }
    #pragma unroll
    for (int off = 32; off; off >>= 1){
      s0 += __shfl_xor(s0, off);
      s1 += __shfl_xor(s1, off);
      s2 += __shfl_xor(s2, off);
    }
    const float mx = fmaxf(fmaxf(s0, s1), s2);
    const float x0 = __expf(s0 - mx), x1 = __expf(s1 - mx), x2 = __expf(s2 - mx);
    const float inv = 1.0f / (x0 + x1 + x2);
    const float pr0 = x0*inv, pr1 = x1*inv, pr2 = x2*inv;

    // ---- GRU (row w, 4 cols/lane, state in regs) ----
    const f16x4 qu = *(const f16x4*)&qg16[w*1032 + 256 + c4];
    const f16x4 qr = *(const f16x4*)&qg16[w*1032 + 512 + c4];
    const f16x4 qc = *(const f16x4*)&qg16[w*1032 + 768 + c4];
    #pragma unroll
    for (int j = 0; j < 4; ++j){
      const float geu = pr2*(float)cU[j] + pr1*(float)U1[j] + pr0*(float)U2[j];
      const float ger = pr2*(float)cR[j] + pr1*(float)R1[j] + pr0*(float)R2[j];
      const float gec = pr2*(float)cC[j] + pr1*(float)C1[j] + pr0*(float)C2[j];
      const float up   = sigmoid_f((float)qu[j] + geu + (float)cNU[j]);
      const float rp   = sigmoid_f((float)qr[j] + ger + (float)cNR[j]);
      const float cand = tanh_f(rp*(float)qc[j] + gec + (float)cNC[j]);
      sn[j] = (1.0f - up)*sn[j] + up*cand;
    }
    { f16x4 h; h[0]=(f16)sn[0]; h[1]=(f16)sn[1]; h[2]=(f16)sn[2]; h[3]=(f16)sn[3]; *(f16x4*)sa = h; }
    if (t == 255) *(f32x4*)(out + (size_t)gb*256 + c4) = sn;
    lgkm_barrier();
  }

  *(f32x4*)(state + (size_t)gb*256 + c4) = sn;
}

// ---------------------------------- launch ----------------------------------
extern "C" void kernel_launch(void* const* d_in, const int* in_sizes, int n_in,
                              void* d_out, int out_size, void* d_ws, size_t ws_size,
                              hipStream_t stream)
{
  const float* X  = (const float*)d_in[0];
  const float* EK = (const float*)d_in[1];
  const float* SK = (const float*)d_in[2];
  const float* BI = (const float*)d_in[3];
  const float* LK = (const float*)d_in[4];
  const float* RS = (const float*)d_in[5];
  const float* RE = (const float*)d_in[6];
  const float* NW = (const float*)d_in[7];
  float* out = (float*)d_out;
  char* ws = (char*)d_ws;

  const size_t slabB = 1024ull * 1792ull * 2ull;   // 3,670,016 B
  const size_t XhB   = 134217728ull;               // 1024*256*256 f16
  const size_t wB    = 917504ull + 524288ull + 1048576ull;
  int CT = 4;
  if      (ws_size >= 34ull*slabB + XhB + wB) CT = 32;
  else if (ws_size >= 18ull*slabB + XhB + wB) CT = 16;
  else if (ws_size >= 10ull*slabB + XhB + wB) CT = 8;

  f16* P = (f16*)ws;
  size_t poff = (size_t)(CT + 2) * slabB;
  f16* Xh    = (f16*)(ws + poff);
  f16* WcatT = (f16*)(ws + poff + XhB);
  f16* WsrF  = (f16*)(ws + poff + XhB + 917504ull);
  float* state = (float*)(ws + poff + XhB + 917504ull + 524288ull);

  hipMemsetAsync(state, 0, 1048576ull, stream);
  hipMemsetAsync(P, 0, 2ull*slabB, stream);        // zero "virtual" slabs t=-2,-1
  cast_x_kernel<<<32768, 256, 0, stream>>>(X, Xh);
  cast_w_kernel<<<2816, 256, 0, stream>>>(EK, RE, NW, SK, RS, WcatT, WsrF);

  const int nch = 256 / CT;
  for (int c = 0; c < nch; ++c){
    const int t0 = c * CT;
    const int t_start  = (c == 0) ? 0 : (t0 - 2);
    const int slab_off = (c == 0) ? 2 : 0;
    const int Mtiles = (((c == 0) ? CT : (CT + 2)) * 1024) / 128;
    gemm_f16_kernel<<<Mtiles * 14, 256, 0, stream>>>(
        Xh, WcatT, P + (size_t)slab_off * 1024 * 1792, Mtiles, t_start);
    recurrent_kernel<<<128, 512, 0, stream>>>(P, WsrF, BI, LK, state, out, t0, CT);
  }
}

// Round 11
// 1752.245 us; speedup vs baseline: 1.9635x; 1.1024x over previous
//
#include <hip/hip_runtime.h>

// AttentionRNN: B=1024, T=256, U=256.
//  Xh = fp16(X); P[t] = x_t @ [Wemb|Wre|Wnew] (fp16 MFMA GEMM, CT chunks).
//  Recurrent v3 (TRULY persistent weights): 128 blocks x 8 rows x 8 waves.
//  Wsr resident: kt0..5 in 192 VGPRs/wave PINNED by keep-alive asm each step
//  (defeats the compiler's rematerialization that left r10 at VGPR_Count=128
//  re-streaming 384KB/step from L2); kt6..7 in 128 KB LDS. Phase 1 runs four
//  quarter-passes (acc[2]) to keep transient VGPR pressure under the 256 cap.

typedef _Float16 f16;
typedef _Float16 f16x8 __attribute__((ext_vector_type(8)));
typedef _Float16 f16x4 __attribute__((ext_vector_type(4)));
typedef float f32x4 __attribute__((ext_vector_type(4)));

static __device__ __forceinline__ f32x4 mfma16(f16x8 a, f16x8 b, f32x4 c){
  return __builtin_amdgcn_mfma_f32_16x16x32_f16(a, b, c, 0, 0, 0);
}
static __device__ __forceinline__ float sigmoid_f(float x){
  return 1.0f / (1.0f + __expf(-x));
}
static __device__ __forceinline__ float tanh_f(float x){
  float e = __expf(2.0f * x);
  return 1.0f - 2.0f / (e + 1.0f);   // stable
}
static __device__ __forceinline__ void lgkm_barrier(){
  asm volatile("s_waitcnt lgkmcnt(0)" ::: "memory");
  __builtin_amdgcn_s_barrier();
}

// ---------------- cast X fp32 -> fp16 (same layout) ----------------
__global__ void cast_x_kernel(const float* __restrict__ X, f16* __restrict__ Xh){
  size_t e = ((size_t)blockIdx.x * 256 + threadIdx.x) * 8;
  f32x4 v0 = *(const f32x4*)(X + e);
  f32x4 v1 = *(const f32x4*)(X + e + 4);
  f16x8 h;
  #pragma unroll
  for (int j = 0; j < 8; ++j) h[j] = (f16)((j < 4) ? v0[j] : v1[j-4]);
  *(f16x8*)(Xh + e) = h;
}

// ------------- cast weights to fp16 -------------
// WcatT rows: [0,256) Wemb^T, [256,1024) Wre^T, [1024,1792) Wnew^T  (N x K row-major)
// WsrF fragment-packed [ct64][kt8][lane64][e8]: col=ct*16+(lane&15), k=kt*32+((lane>>4)&3)*8+e
__global__ void cast_w_kernel(const float* __restrict__ EK, const float* __restrict__ RE,
    const float* __restrict__ NW, const float* __restrict__ SK, const float* __restrict__ RS,
    f16* __restrict__ WcatT, f16* __restrict__ WsrF){
  int tid = blockIdx.x * 256 + threadIdx.x;
  if (tid < 458752){
    int n = tid >> 8, k = tid & 255;
    float v;
    if (n < 256)       v = EK[k*256 + n];
    else if (n < 1024) v = RE[k*768 + (n-256)];
    else               v = NW[k*768 + (n-1024)];
    WcatT[n*256 + k] = (f16)v;
  } else {
    int idx = tid - 458752;            // 0..262143
    int e    = idx & 7;
    int lane = (idx >> 3) & 63;
    int kt   = (idx >> 9) & 7;
    int ct   = idx >> 12;              // 0..63
    int col  = ct*16 + (lane & 15);
    int k    = kt*32 + ((lane >> 4) & 3)*8 + e;
    float v = (col < 256) ? SK[k*256 + col] : RS[k*768 + (col-256)];
    WsrF[idx] = (f16)v;
  }
}

// ---- GEMM: C[r=tsl*1024+b][0:1792) = Xh[b][t_start+tsl][:] @ WcatT^T ----
__global__ __launch_bounds__(256, 2) void gemm_f16_kernel(
    const f16* __restrict__ Xh, const f16* __restrict__ Bm,
    f16* __restrict__ C, int Mtiles, int t_start)
{
  __shared__ f16 As[128*64];
  __shared__ f16 Bs[128*64];
  const int NT = 14;
  const int nwg = Mtiles * NT;
  int bid = blockIdx.x, wg = bid;
  if ((nwg & 7) == 0){ int cpx = nwg >> 3; wg = (bid & 7) * cpx + (bid >> 3); }
  const int mt = wg / NT, nt = wg % NT;
  const int tsl = mt >> 3;
  const int b0  = (mt & 7) * 128;
  const int t   = t_start + tsl;
  const int n0  = nt * 128;
  const int tid = threadIdx.x;
  const int l = tid & 63, wid = tid >> 6;
  const int wr = wid >> 1, wc = wid & 1;
  const int srow = tid >> 3;
  const int scol = (tid & 7) * 8;

  const size_t ASTR = 32ull * 65536ull;
  const f16* Ab = Xh + ((size_t)(b0 + srow) * 256 + t) * 256 + scol;
  const f16* Bb = Bm + ((size_t)(n0 + srow)) * 256 + scol;

  f16x8 ra[4], rb[4];
  #pragma unroll
  for (int j = 0; j < 4; ++j){
    ra[j] = *(const f16x8*)(Ab + (size_t)j * ASTR);
    rb[j] = *(const f16x8*)(Bb + (size_t)j * 32 * 256);
  }

  f32x4 acc[4][4];
  #pragma unroll
  for (int mi = 0; mi < 4; ++mi)
    #pragma unroll
    for (int ni = 0; ni < 4; ++ni)
      acc[mi][ni] = (f32x4){0.f,0.f,0.f,0.f};

  for (int kt = 0; kt < 4; ++kt){
    #pragma unroll
    for (int j = 0; j < 4; ++j){
      int row = srow + j*32;
      int e = (row*64 + scol) ^ ((row & 7) << 3);
      *(f16x8*)&As[e] = ra[j];
      *(f16x8*)&Bs[e] = rb[j];
    }
    __syncthreads();
    if (kt < 3){
      #pragma unroll
      for (int j = 0; j < 4; ++j){
        ra[j] = *(const f16x8*)(Ab + (kt+1)*64 + (size_t)j * ASTR);
        rb[j] = *(const f16x8*)(Bb + (kt+1)*64 + (size_t)j * 32 * 256);
      }
    }
    #pragma unroll
    for (int kk = 0; kk < 2; ++kk){
      f16x8 af[4], bfr[4];
      #pragma unroll
      for (int mi = 0; mi < 4; ++mi){
        int row = wr*64 + mi*16 + (l & 15);
        int e = (row*64 + kk*32 + (l >> 4)*8) ^ ((row & 7) << 3);
        af[mi] = *(const f16x8*)&As[e];
      }
      #pragma unroll
      for (int ni = 0; ni < 4; ++ni){
        int row = wc*64 + ni*16 + (l & 15);
        int e = (row*64 + kk*32 + (l >> 4)*8) ^ ((row & 7) << 3);
        bfr[ni] = *(const f16x8*)&Bs[e];
      }
      #pragma unroll
      for (int mi = 0; mi < 4; ++mi)
        #pragma unroll
        for (int ni = 0; ni < 4; ++ni)
          acc[mi][ni] = mfma16(af[mi], bfr[ni], acc[mi][ni]);
    }
    __syncthreads();
  }
  const size_t m0 = (size_t)mt * 128;
  #pragma unroll
  for (int mi = 0; mi < 4; ++mi){
    #pragma unroll
    for (int ni = 0; ni < 4; ++ni){
      int col = n0 + wc*64 + ni*16 + (l & 15);
      size_t row = m0 + wr*64 + mi*16 + ((l >> 4) * 4);
      #pragma unroll
      for (int j = 0; j < 4; ++j)
        C[(row + j) * 1792 + col] = (f16)acc[mi][ni][j];
    }
  }
}

// ---------- recurrent v3: 128 blocks x 8 rows, 512 threads (8 waves) ----------
__global__ __launch_bounds__(512, 1) void recurrent_kernel(
    const f16* __restrict__ P, const f16* __restrict__ WsrF,
    const float* __restrict__ bias, const float* __restrict__ Lk,
    float* __restrict__ state, float* __restrict__ out,
    int t0, int nsteps)
{
  __shared__ f16 Wl[8*8192];             // weights kt6..7: [w][ct*2+(kt-6)][lane][8] = 128 KB
  __shared__ f16 qg16[8*1032];           // qg as f16: [row][1032]
  __shared__ f16 stA[8*520];             // state f16, fragment-major [kt][lane][8]
  __shared__ __align__(16) float sb[256];
  __shared__ __align__(16) float sl[256];

  const int tid = threadIdx.x;
  const int l = tid & 63, w = tid >> 6;  // 8 waves, wave w owns row w
  const int r0 = blockIdx.x * 8;
  const int arow = l & 15, agrp = l >> 4;
  const int c4 = l * 4;
  const int gb = r0 + w;
  const size_t SL = 1024ull*1792ull;
  const size_t gbo = (size_t)gb*1792;

  if (tid < 256){ sb[tid] = bias[tid]; sl[tid] = Lk[tid]; }
  for (int j = tid; j < 8*520; j += 512) stA[j] = (f16)0.f;

  // ---- persistent weights: kt0..5 -> 192 VGPRs/wave ----
  const f16* const wbase = WsrF + (size_t)w*32768 + l*8;   // wave's 8 ct-tiles
  f16x8 Wreg[8][6];
  #pragma unroll
  for (int ct = 0; ct < 8; ++ct)
    #pragma unroll
    for (int kt = 0; kt < 6; ++kt)
      Wreg[ct][kt] = *(const f16x8*)(wbase + (ct*8 + kt)*512);
  // ---- kt6..7 -> LDS (128 KB, loaded once) ----
  #pragma unroll
  for (int ct = 0; ct < 8; ++ct)
    #pragma unroll
    for (int k2 = 0; k2 < 2; ++k2)
      *(f16x8*)&Wl[w*8192 + (ct*2 + k2)*512 + l*8] =
          *(const f16x8*)(wbase + (ct*8 + 6 + k2)*512);
  __syncthreads();

  f32x4 sn = *(const f32x4*)(state + (size_t)gb*256 + c4);
  f16* const sa = &stA[(l >> 3)*520 + ((((l >> 1) & 3) << 4) + w)*8 + (l & 1)*4];
  { f16x4 h; h[0]=(f16)sn[0]; h[1]=(f16)sn[1]; h[2]=(f16)sn[2]; h[3]=(f16)sn[3]; *(f16x4*)sa = h; }
  lgkm_barrier();

  for (int i = 0; i < nsteps; ++i){
    const int t = t0 + i;
    const f16* p2 = P + (size_t)(i+2)*SL + gbo;
    const f16* p1 = P + (size_t)(i+1)*SL + gbo;
    const f16* p0 = P + (size_t)(i+0)*SL + gbo;

    // ---- keep-alive: force Wreg resident across the step loop (defeats the
    //      rematerialization that made r10 re-stream 384KB/step from L2) ----
    #pragma unroll
    for (int ct = 0; ct < 8; ++ct)
      #pragma unroll
      for (int kt = 0; kt < 6; ++kt)
        asm volatile("" : "+v"(Wreg[ct][kt]));

    // ---- cold P loads (slab i+2, HBM): issued first, consumed in phase 2 ----
    const f16x4 cE2 = *(const f16x4*)(p2 + c4);
    const f16x4 cU  = *(const f16x4*)(p2 +  256 + c4);
    const f16x4 cR  = *(const f16x4*)(p2 +  512 + c4);
    const f16x4 cC  = *(const f16x4*)(p2 +  768 + c4);
    const f16x4 cNU = *(const f16x4*)(p2 + 1024 + c4);
    const f16x4 cNR = *(const f16x4*)(p2 + 1280 + c4);
    const f16x4 cNC = *(const f16x4*)(p2 + 1536 + c4);

    // ---- phase 1: qg = state @ Wsr, four quarter-passes (acc[2] = low pressure) ----
    #pragma unroll
    for (int qtr = 0; qtr < 4; ++qtr){
      f32x4 acc[2];
      acc[0] = (f32x4){0.f,0.f,0.f,0.f};
      acc[1] = acc[0];
      #pragma unroll
      for (int kt = 0; kt < 8; ++kt){
        const f16x8 av = *(const f16x8*)&stA[kt*520 + l*8];
        #pragma unroll
        for (int c = 0; c < 2; ++c){
          const int ct = qtr*2 + c;
          f16x8 B;
          if (kt < 6) B = Wreg[ct][kt];
          else        B = *(const f16x8*)&Wl[w*8192 + (ct*2 + (kt-6))*512 + l*8];
          acc[c] = mfma16(av, B, acc[c]);
        }
      }
      if (agrp < 2){
        #pragma unroll
        for (int c = 0; c < 2; ++c){
          const int col = w*128 + (qtr*2 + c)*16 + arow;
          #pragma unroll
          for (int j = 0; j < 4; ++j)
            qg16[(agrp*4 + j)*1032 + col] = (f16)acc[c][j];
        }
      }
    }
    lgkm_barrier();

    // ---- warm P loads (slabs i, i+1: L2-resident from prior steps) ----
    const f16x4 E0 = *(const f16x4*)(p0 + c4);
    const f16x4 E1 = *(const f16x4*)(p1 + c4);
    const f16x4 U1 = *(const f16x4*)(p1 + 256 + c4);
    const f16x4 R1 = *(const f16x4*)(p1 + 512 + c4);
    const f16x4 C1 = *(const f16x4*)(p1 + 768 + c4);
    const f16x4 U2 = *(const f16x4*)(p0 + 256 + c4);
    const f16x4 R2 = *(const f16x4*)(p0 + 512 + c4);
    const f16x4 C2 = *(const f16x4*)(p0 + 768 + c4);

    // ---- scores + softmax (full wave on row w) ----
    const f16x4 qv = *(const f16x4*)&qg16[w*1032 + c4];
    const f32x4 bb = *(const f32x4*)&sb[c4];
    const f32x4 lk = *(const f32x4*)&sl[c4];
    float s0 = 0.f, s1 = 0.f, s2 = 0.f;
    #pragma unroll
    for (int j = 0; j < 4; ++j){
      const float qb = (float)qv[j] + bb[j];
      s0 += tanh_f((float)E0[j]  + qb) * lk[j];
      s1 += tanh_f((float)E1[j]  + qb) * lk[j];
      s2 += tanh_f((float)cE2[j] + qb) * lk[j];
    }
    #pragma unroll
    for (int off = 32; off; off >>= 1){
      s0 += __shfl_xor(s0, off);
      s1 += __shfl_xor(s1, off);
      s2 += __shfl_xor(s2, off);
    }
    const float mx = fmaxf(fmaxf(s0, s1), s2);
    const float x0 = __expf(s0 - mx), x1 = __expf(s1 - mx), x2 = __expf(s2 - mx);
    const float inv = 1.0f / (x0 + x1 + x2);
    const float pr0 = x0*inv, pr1 = x1*inv, pr2 = x2*inv;

    // ---- GRU (row w, 4 cols/lane, state in regs) ----
    const f16x4 qu = *(const f16x4*)&qg16[w*1032 + 256 + c4];
    const f16x4 qr = *(const f16x4*)&qg16[w*1032 + 512 + c4];
    const f16x4 qc = *(const f16x4*)&qg16[w*1032 + 768 + c4];
    #pragma unroll
    for (int j = 0; j < 4; ++j){
      const float geu = pr2*(float)cU[j] + pr1*(float)U1[j] + pr0*(float)U2[j];
      const float ger = pr2*(float)cR[j] + pr1*(float)R1[j] + pr0*(float)R2[j];
      const float gec = pr2*(float)cC[j] + pr1*(float)C1[j] + pr0*(float)C2[j];
      const float up   = sigmoid_f((float)qu[j] + geu + (float)cNU[j]);
      const float rp   = sigmoid_f((float)qr[j] + ger + (float)cNR[j]);
      const float cand = tanh_f(rp*(float)qc[j] + gec + (float)cNC[j]);
      sn[j] = (1.0f - up)*sn[j] + up*cand;
    }
    { f16x4 h; h[0]=(f16)sn[0]; h[1]=(f16)sn[1]; h[2]=(f16)sn[2]; h[3]=(f16)sn[3]; *(f16x4*)sa = h; }
    if (t == 255) *(f32x4*)(out + (size_t)gb*256 + c4) = sn;
    lgkm_barrier();
  }

  *(f32x4*)(state + (size_t)gb*256 + c4) = sn;
}

// ---------------------------------- launch ----------------------------------
extern "C" void kernel_launch(void* const* d_in, const int* in_sizes, int n_in,
                              void* d_out, int out_size, void* d_ws, size_t ws_size,
                              hipStream_t stream)
{
  const float* X  = (const float*)d_in[0];
  const float* EK = (const float*)d_in[1];
  const float* SK = (const float*)d_in[2];
  const float* BI = (const float*)d_in[3];
  const float* LK = (const float*)d_in[4];
  const float* RS = (const float*)d_in[5];
  const float* RE = (const float*)d_in[6];
  const float* NW = (const float*)d_in[7];
  float* out = (float*)d_out;
  char* ws = (char*)d_ws;

  const size_t slabB = 1024ull * 1792ull * 2ull;   // 3,670,016 B
  const size_t XhB   = 134217728ull;               // 1024*256*256 f16
  const size_t wB    = 917504ull + 524288ull + 1048576ull;
  int CT = 4;
  if      (ws_size >= 34ull*slabB + XhB + wB) CT = 32;
  else if (ws_size >= 18ull*slabB + XhB + wB) CT = 16;
  else if (ws_size >= 10ull*slabB + XhB + wB) CT = 8;

  f16* P = (f16*)ws;
  size_t poff = (size_t)(CT + 2) * slabB;
  f16* Xh    = (f16*)(ws + poff);
  f16* WcatT = (f16*)(ws + poff + XhB);
  f16* WsrF  = (f16*)(ws + poff + XhB + 917504ull);
  float* state = (float*)(ws + poff + XhB + 917504ull + 524288ull);

  hipMemsetAsync(state, 0, 1048576ull, stream);
  hipMemsetAsync(P, 0, 2ull*slabB, stream);        // zero "virtual" slabs t=-2,-1
  cast_x_kernel<<<32768, 256, 0, stream>>>(X, Xh);
  cast_w_kernel<<<2816, 256, 0, stream>>>(EK, RE, NW, SK, RS, WcatT, WsrF);

  const int nch = 256 / CT;
  for (int c = 0; c < nch; ++c){
    const int t0 = c * CT;
    const int t_start  = (c == 0) ? 0 : (t0 - 2);
    const int slab_off = (c == 0) ? 2 : 0;
    const int Mtiles = (((c == 0) ? CT : (CT + 2)) * 1024) / 128;
    gemm_f16_kernel<<<Mtiles * 14, 256, 0, stream>>>(
        Xh, WcatT, P + (size_t)slab_off * 1024 * 1792, Mtiles, t_start);
    recurrent_kernel<<<128, 512, 0, stream>>>(P, WsrF, BI, LK, state, out, t0, CT);
  }
}